// Round 1
// baseline (84.485 us; speedup 1.0000x reference)
//
#include <hip/hip_runtime.h>
#include <stdint.h>

// IDs are in [0, 100000): 100000 bits -> 3125 u32 words = 12.5 KB per bitset.
#define NWORDS 3125

__global__ void zero_ws_kernel(uint32_t* __restrict__ w, int n) {
    int i = blockIdx.x * blockDim.x + threadIdx.x;
    if (i < n) w[i] = 0u;
}

__global__ void build_hr_kernel(const int* __restrict__ neg, int B,
                                uint32_t* __restrict__ headb,
                                uint32_t* __restrict__ relb) {
    int b = blockIdx.x * blockDim.x + threadIdx.x;
    if (b >= B) return;
    int h = neg[b * 3 + 0];
    int r = neg[b * 3 + 1];
    atomicOr(&headb[h >> 5], 1u << (h & 31));
    atomicOr(&relb[r >> 5], 1u << (r & 31));
}

// Stream mapped_triples; for triples whose (head,rel) are both present in the
// negative-batch bitsets, mark the tail bit. Head/rel bitsets are staged in
// LDS; the tail bitset is accumulated per-block in LDS and flushed once.
__global__ __launch_bounds__(256) void scan_triples_kernel(
        const int* __restrict__ mt, int N,
        const uint32_t* __restrict__ headb,
        const uint32_t* __restrict__ relb,
        uint32_t* __restrict__ tailb) {
    __shared__ uint32_t sh[NWORDS];
    __shared__ uint32_t sr[NWORDS];
    __shared__ uint32_t st[NWORDS];
    for (int i = threadIdx.x; i < NWORDS; i += blockDim.x) {
        sh[i] = headb[i];
        sr[i] = relb[i];
        st[i] = 0u;
    }
    __syncthreads();

    const int tid = blockIdx.x * blockDim.x + threadIdx.x;
    const int stride = gridDim.x * blockDim.x;
    const int ngroups = N >> 2;  // groups of 4 triples = 12 ints = 3 x int4
    const int4* __restrict__ mt4 = (const int4*)mt;

    for (int g = tid; g < ngroups; g += stride) {
        int4 a = mt4[g * 3 + 0];
        int4 b = mt4[g * 3 + 1];
        int4 c = mt4[g * 3 + 2];
        int hs[4] = {a.x, a.w, b.z, c.y};
        int rs[4] = {a.y, b.x, b.w, c.z};
        int ts[4] = {a.z, b.y, c.x, c.w};
#pragma unroll
        for (int k = 0; k < 4; ++k) {
            int h = hs[k], r = rs[k], t = ts[k];
            if ((sh[h >> 5] >> (h & 31)) & 1u) {
                if ((sr[r >> 5] >> (r & 31)) & 1u) {
                    uint32_t bit = 1u << (t & 31);
                    // read-first: skip the LDS atomic once the bit is set
                    if (!(st[t >> 5] & bit)) atomicOr(&st[t >> 5], bit);
                }
            }
        }
    }

    // remainder triples (N not divisible by 4)
    int base = ngroups << 2;
    for (int i = base + tid; i < N; i += stride) {
        int h = mt[i * 3 + 0], r = mt[i * 3 + 1], t = mt[i * 3 + 2];
        if (((sh[h >> 5] >> (h & 31)) & 1u) && ((sr[r >> 5] >> (r & 31)) & 1u)) {
            uint32_t bit = 1u << (t & 31);
            if (!(st[t >> 5] & bit)) atomicOr(&st[t >> 5], bit);
        }
    }

    __syncthreads();
    for (int i = threadIdx.x; i < NWORDS; i += blockDim.x) {
        uint32_t v = st[i];
        if (v) atomicOr(&tailb[i], v);
    }
}

__global__ void finalize_kernel(const int* __restrict__ neg, int B,
                                const uint32_t* __restrict__ tailb,
                                int* __restrict__ out) {
    int b = blockIdx.x * blockDim.x + threadIdx.x;
    if (b >= B) return;
    int h = neg[b * 3 + 0];
    int r = neg[b * 3 + 1];
    int t = neg[b * 3 + 2];
    bool filtered = (tailb[t >> 5] >> (t & 31)) & 1u;
    int keep = filtered ? 0 : 1;
    out[b * 3 + 0] = keep ? h : -1;
    out[b * 3 + 1] = keep ? r : -1;
    out[b * 3 + 2] = keep ? t : -1;
    out[3 * B + b] = keep;  // keep_mask as 0/1 int32
}

extern "C" void kernel_launch(void* const* d_in, const int* in_sizes, int n_in,
                              void* d_out, int out_size, void* d_ws, size_t ws_size,
                              hipStream_t stream) {
    const int* neg = (const int*)d_in[0];   // [B,3] int32
    const int* mt  = (const int*)d_in[1];   // [N,3] int32
    int B = in_sizes[0] / 3;
    int N = in_sizes[1] / 3;
    int* out = (int*)d_out;

    uint32_t* ws    = (uint32_t*)d_ws;
    uint32_t* headb = ws;
    uint32_t* relb  = ws + NWORDS;
    uint32_t* tailb = ws + 2 * NWORDS;

    // 1) zero the three bitsets (ws is NOT re-poisoned between replays)
    zero_ws_kernel<<<(3 * NWORDS + 255) / 256, 256, 0, stream>>>(ws, 3 * NWORDS);
    // 2) build head/rel presence bitsets from the negative batch
    build_hr_kernel<<<(B + 255) / 256, 256, 0, stream>>>(neg, B, headb, relb);
    // 3) stream all triples, mark surviving tails
    scan_triples_kernel<<<1024, 256, 0, stream>>>(mt, N, headb, relb, tailb);
    // 4) produce filtered batch + keep mask
    finalize_kernel<<<(B + 255) / 256, 256, 0, stream>>>(neg, B, tailb, out);
}

// Round 2
// 58.518 us; speedup vs baseline: 1.4437x; 1.4437x over previous
//
#include <hip/hip_runtime.h>
#include <stdint.h>

// IDs are in [0, 100000): 100000 bits -> 3125 u32 words = 12.5 KB per bitset.
#define NWORDS 3125
#define SCAN_BLOCKS 1024
#define SCAN_THREADS 512
#define REDUCE_CHUNK 64   // copies OR'd per reduce thread
#define REDUCE_NCHUNK (SCAN_BLOCKS / REDUCE_CHUNK)  // 16

__global__ void zero_ws_kernel(uint32_t* __restrict__ w, int n) {
    int i = blockIdx.x * blockDim.x + threadIdx.x;
    if (i < n) w[i] = 0u;
}

__global__ void build_hr_kernel(const int* __restrict__ neg, int B,
                                uint32_t* __restrict__ headb,
                                uint32_t* __restrict__ relb) {
    int b = blockIdx.x * blockDim.x + threadIdx.x;
    if (b >= B) return;
    int h = neg[b * 3 + 0];
    int r = neg[b * 3 + 1];
    atomicOr(&headb[h >> 5], 1u << (h & 31));
    atomicOr(&relb[r >> 5], 1u << (r & 31));
}

// Stream mapped_triples; for triples whose (head,rel) are both present in the
// negative-batch bitsets, mark the tail bit in a per-block LDS bitset.
// Each block then WRITES its private bitset to ws (no atomics) for a later
// OR-reduce kernel. head/rel bitsets staged in LDS for fast random gather.
__global__ __launch_bounds__(SCAN_THREADS, 8) void scan_triples_kernel(
        const int* __restrict__ mt, int N,
        const uint32_t* __restrict__ headb,
        const uint32_t* __restrict__ relb,
        uint32_t* __restrict__ st_copies) {
    __shared__ uint32_t sh[NWORDS];
    __shared__ uint32_t sr[NWORDS];
    __shared__ uint32_t st[NWORDS];
    for (int i = threadIdx.x; i < NWORDS; i += blockDim.x) {
        sh[i] = headb[i];
        sr[i] = relb[i];
        st[i] = 0u;
    }
    __syncthreads();

    const int tid = blockIdx.x * blockDim.x + threadIdx.x;
    const int stride = gridDim.x * blockDim.x;
    const int ngroups = N >> 2;  // groups of 4 triples = 12 ints = 3 x int4
    const int4* __restrict__ mt4 = (const int4*)mt;

    for (int g = tid; g < ngroups; g += stride) {
        int4 a = mt4[g * 3 + 0];
        int4 b = mt4[g * 3 + 1];
        int4 c = mt4[g * 3 + 2];
        int hs[4] = {a.x, a.w, b.z, c.y};
        int rs[4] = {a.y, b.x, b.w, c.z};
        int ts[4] = {a.z, b.y, c.x, c.w};
#pragma unroll
        for (int k = 0; k < 4; ++k) {
            int h = hs[k], r = rs[k], t = ts[k];
            // branchless h&r test: both gathers issue independently
            uint32_t hb = (sh[h >> 5] >> (h & 31)) & 1u;
            uint32_t rb = (sr[r >> 5] >> (r & 31)) & 1u;
            if (hb & rb) {
                uint32_t bit = 1u << (t & 31);
                // read-first: skip the LDS atomic once the bit is set
                if (!(st[t >> 5] & bit)) atomicOr(&st[t >> 5], bit);
            }
        }
    }

    // remainder triples (N not divisible by 4)
    int base = ngroups << 2;
    for (int i = base + tid; i < N; i += stride) {
        int h = mt[i * 3 + 0], r = mt[i * 3 + 1], t = mt[i * 3 + 2];
        if (((sh[h >> 5] >> (h & 31)) & 1u) && ((sr[r >> 5] >> (r & 31)) & 1u)) {
            uint32_t bit = 1u << (t & 31);
            if (!(st[t >> 5] & bit)) atomicOr(&st[t >> 5], bit);
        }
    }

    __syncthreads();
    // plain coalesced store of the private bitset; reduce kernel ORs them
    uint32_t* dst = st_copies + (size_t)blockIdx.x * NWORDS;
    for (int i = threadIdx.x; i < NWORDS; i += blockDim.x) dst[i] = st[i];
}

// OR-reduce the SCAN_BLOCKS private tail bitsets into tailb.
// thread = (word i, chunk c): ORs REDUCE_CHUNK copies, one atomicOr per chunk.
__global__ void reduce_tails_kernel(const uint32_t* __restrict__ st_copies,
                                    uint32_t* __restrict__ tailb) {
    int idx = blockIdx.x * blockDim.x + threadIdx.x;
    int total = NWORDS * REDUCE_NCHUNK;
    if (idx >= total) return;
    int i = idx % NWORDS;         // word index (consecutive threads -> coalesced)
    int c0 = (idx / NWORDS) * REDUCE_CHUNK;
    uint32_t acc = 0u;
    for (int c = 0; c < REDUCE_CHUNK; ++c)
        acc |= st_copies[(size_t)(c0 + c) * NWORDS + i];
    if (acc) atomicOr(&tailb[i], acc);
}

__global__ void finalize_kernel(const int* __restrict__ neg, int B,
                                const uint32_t* __restrict__ tailb,
                                int* __restrict__ out) {
    int b = blockIdx.x * blockDim.x + threadIdx.x;
    if (b >= B) return;
    int h = neg[b * 3 + 0];
    int r = neg[b * 3 + 1];
    int t = neg[b * 3 + 2];
    bool filtered = (tailb[t >> 5] >> (t & 31)) & 1u;
    int keep = filtered ? 0 : 1;
    out[b * 3 + 0] = keep ? h : -1;
    out[b * 3 + 1] = keep ? r : -1;
    out[b * 3 + 2] = keep ? t : -1;
    out[3 * B + b] = keep;  // keep_mask as 0/1 int32
}

extern "C" void kernel_launch(void* const* d_in, const int* in_sizes, int n_in,
                              void* d_out, int out_size, void* d_ws, size_t ws_size,
                              hipStream_t stream) {
    const int* neg = (const int*)d_in[0];   // [B,3] int32
    const int* mt  = (const int*)d_in[1];   // [N,3] int32
    int B = in_sizes[0] / 3;
    int N = in_sizes[1] / 3;
    int* out = (int*)d_out;

    uint32_t* ws       = (uint32_t*)d_ws;
    uint32_t* headb    = ws;
    uint32_t* relb     = ws + NWORDS;
    uint32_t* tailb    = ws + 2 * NWORDS;
    uint32_t* st_copies = ws + 3 * NWORDS;  // SCAN_BLOCKS * NWORDS words (~12.8 MB)

    // 1) zero the three shared bitsets (ws is NOT re-poisoned between replays;
    //    st_copies is fully overwritten by scan, no zeroing needed)
    zero_ws_kernel<<<(3 * NWORDS + 255) / 256, 256, 0, stream>>>(ws, 3 * NWORDS);
    // 2) build head/rel presence bitsets from the negative batch
    build_hr_kernel<<<(B + 255) / 256, 256, 0, stream>>>(neg, B, headb, relb);
    // 3) stream all triples, mark surviving tails into per-block private bitsets
    scan_triples_kernel<<<SCAN_BLOCKS, SCAN_THREADS, 0, stream>>>(
        mt, N, headb, relb, st_copies);
    // 4) OR-reduce private bitsets into tailb
    {
        int total = NWORDS * REDUCE_NCHUNK;
        reduce_tails_kernel<<<(total + 255) / 256, 256, 0, stream>>>(st_copies, tailb);
    }
    // 5) produce filtered batch + keep mask
    finalize_kernel<<<(B + 255) / 256, 256, 0, stream>>>(neg, B, tailb, out);
}